// Round 6
// baseline (87.543 us; speedup 1.0000x reference)
//
#include <hip/hip_runtime.h>
#include <hip/hip_fp16.h>
#include <math.h>

#define NROWS 50000
#define D 128
#define KNB 16

typedef _Float16 f16;
typedef _Float16 f16x8 __attribute__((ext_vector_type(8)));
typedef float f32x4 __attribute__((ext_vector_type(4)));

// ---- gemm: stage W2(f16,swizzled,32KB); per wave 16 rows: fph(f16), inv_norm, baseh(f16) ----
__global__ __launch_bounds__(512) void gemm_kernel(const float* __restrict__ fp,
                                                   const float* __restrict__ W,
                                                   const float* __restrict__ b,
                                                   f16* __restrict__ fph,
                                                   f16* __restrict__ baseh,
                                                   float* __restrict__ inv_norm) {
    __shared__ f16 wlds[128 * 128];  // W2[col][k], chunk-swizzled: chunk ^= (col&15)
    int tid = threadIdx.x;
    #pragma unroll
    for (int it = 0; it < 4; ++it) {
        int g = tid + it * 512;
        int i = g * 8;                 // 0..16383
        int c = i >> 7;                // output col 0..127
        int k0 = i & 127;
        int chunk = (k0 >> 3) ^ (c & 15);
        f32x4 v0 = *(const f32x4*)(W + (size_t)c * 256 + 128 + k0);
        f32x4 v1 = *(const f32x4*)(W + (size_t)c * 256 + 128 + k0 + 4);
        f16x8 h;
        #pragma unroll
        for (int e = 0; e < 4; ++e) { h[e] = (f16)v0[e]; h[4 + e] = (f16)v1[e]; }
        *(f16x8*)(wlds + c * 128 + chunk * 8) = h;
    }
    __syncthreads();

    int wid = tid >> 6, lane = tid & 63;
    int row0 = blockIdx.x * 128 + wid * 16;
    if (row0 >= NROWS) return;         // no barriers after this point
    int r = lane & 15, kg = lane >> 4;

    const float* src = fp + (size_t)(row0 + r) * D + kg * 8;
    f32x4 v[8];
    float ssq = 0.f;
    #pragma unroll
    for (int kc = 0; kc < 4; ++kc) {
        v[2 * kc]     = *(const f32x4*)(src + kc * 32);
        v[2 * kc + 1] = *(const f32x4*)(src + kc * 32 + 4);
        #pragma unroll
        for (int e = 0; e < 4; ++e) {
            ssq = fmaf(v[2 * kc][e], v[2 * kc][e], ssq);
            ssq = fmaf(v[2 * kc + 1][e], v[2 * kc + 1][e], ssq);
        }
    }
    ssq += __shfl_xor(ssq, 16, 64);
    ssq += __shfl_xor(ssq, 32, 64);
    if (kg == 0) inv_norm[row0 + r] = rsqrtf(ssq);

    f16x8 a[4];
    #pragma unroll
    for (int kc = 0; kc < 4; ++kc) {
        f16x8 h;
        #pragma unroll
        for (int e = 0; e < 4; ++e) { h[e] = (f16)v[2 * kc][e]; h[4 + e] = (f16)v[2 * kc + 1][e]; }
        a[kc] = h;
        *(f16x8*)(fph + (size_t)(row0 + r) * D + kc * 32 + kg * 8) = h;
    }

    #pragma unroll
    for (int ct = 0; ct < 8; ++ct) {
        int col = ct * 16 + r;
        f32x4 acc = {0.f, 0.f, 0.f, 0.f};
        #pragma unroll
        for (int kc = 0; kc < 4; ++kc) {
            int sc = (kc * 4 + kg) ^ r;  // matches staging XOR
            f16x8 bf = *(const f16x8*)(wlds + col * 128 + sc * 8);
            acc = __builtin_amdgcn_mfma_f32_16x16x32_f16(a[kc], bf, acc, 0, 0, 0);
        }
        float bias = b[col];
        #pragma unroll
        for (int i = 0; i < 4; ++i)
            baseh[(size_t)(row0 + kg * 4 + i) * D + col] = (f16)(acc[i] + bias);
    }
}

// ---- main: stage W1 in LDS; 2 n's per wave-pass; Y recomputed via MFMA from gathered fph ----
// Cosine also via MFMA (B = broadcast fph[n]) -> w lands in C/D lane layout, no shuffles.
__global__ __launch_bounds__(256) void main_kernel(const float* __restrict__ W,
                                                   const f16* __restrict__ fph,
                                                   const f16* __restrict__ baseh,
                                                   const int* __restrict__ idx,
                                                   const float* __restrict__ inv_norm,
                                                   float* __restrict__ out) {
    __shared__ f16 wlds[128 * 128];  // W1[col][k], chunk-swizzled
    int tid = threadIdx.x;
    #pragma unroll
    for (int it = 0; it < 8; ++it) {
        int g = tid + it * 256;
        int i = g * 8;
        int c = i >> 7;
        int k0 = i & 127;
        int chunk = (k0 >> 3) ^ (c & 15);
        f32x4 v0 = *(const f32x4*)(W + (size_t)c * 256 + k0);
        f32x4 v1 = *(const f32x4*)(W + (size_t)c * 256 + k0 + 4);
        f16x8 h;
        #pragma unroll
        for (int e = 0; e < 4; ++e) { h[e] = (f16)v0[e]; h[4 + e] = (f16)v1[e]; }
        *(f16x8*)(wlds + c * 128 + chunk * 8) = h;
    }
    __syncthreads();

    int wid = tid >> 6, lane = tid & 63;
    int r = lane & 15, kg = lane >> 4;
    int gw = blockIdx.x * 4 + wid;       // 0..4999

    for (int p = gw; p < NROWS / 2; p += 5000) {
        int n0 = 2 * p, n1 = n0 + 1;
        int ja = idx[(size_t)n0 * KNB + r];
        int jb = idx[(size_t)n1 * KNB + r];

        // A-frags: 16 gathered neighbor rows per n (full row consumed across kg,kc)
        f16x8 aa[4], ab[4];
        #pragma unroll
        for (int kc = 0; kc < 4; ++kc) {
            aa[kc] = *(const f16x8*)(fph + (size_t)ja * D + kc * 32 + kg * 8);
            ab[kc] = *(const f16x8*)(fph + (size_t)jb * D + kc * 32 + kg * 8);
        }
        // inv_norm for the k-indices this lane's C/D rows correspond to (k = kg*4+i)
        float rja[4], rjb[4];
        #pragma unroll
        for (int i = 0; i < 4; ++i) {
            int jai = __shfl(ja, kg * 4 + i, 64);
            int jbi = __shfl(jb, kg * 4 + i, 64);
            rja[i] = inv_norm[jai];
            rjb[i] = inv_norm[jbi];
        }
        float rna = inv_norm[n0], rnb = inv_norm[n1];

        // cosine via MFMA: B[col][k] = fph[n][k] for all cols -> C[kg*4+i][*] = dot(fp[j_k], fp[n])
        f32x4 ca = {0.f, 0.f, 0.f, 0.f}, cb = {0.f, 0.f, 0.f, 0.f};
        #pragma unroll
        for (int kc = 0; kc < 4; ++kc) {
            f16x8 y = *(const f16x8*)(fph + (size_t)n0 * D + kc * 32 + kg * 8);
            ca = __builtin_amdgcn_mfma_f32_16x16x32_f16(aa[kc], y, ca, 0, 0, 0);
        }
        #pragma unroll
        for (int kc = 0; kc < 4; ++kc) {
            f16x8 y = *(const f16x8*)(fph + (size_t)n1 * D + kc * 32 + kg * 8);
            cb = __builtin_amdgcn_mfma_f32_16x16x32_f16(ab[kc], y, cb, 0, 0, 0);
        }
        float wa[4], wb[4];
        #pragma unroll
        for (int i = 0; i < 4; ++i) {
            wa[i] = ca[i] * rna * rja[i];
            wb[i] = cb[i] * rnb * rjb[i];
        }
        // base prefetch: lane needs cols {ct*16 + r}
        float bha[8], bhb[8];
        #pragma unroll
        for (int ct = 0; ct < 8; ++ct) {
            bha[ct] = (float)baseh[(size_t)n0 * D + ct * 16 + r];
            bhb[ct] = (float)baseh[(size_t)n1 * D + ct * 16 + r];
        }
        // Y-recompute + combine, one 16-col tile at a time; ds_reads shared by both n's
        #pragma unroll
        for (int ct = 0; ct < 8; ++ct) {
            f32x4 acc0 = {0.f, 0.f, 0.f, 0.f}, acc1 = {0.f, 0.f, 0.f, 0.f};
            #pragma unroll
            for (int kc = 0; kc < 4; ++kc) {
                int sc = (kc * 4 + kg) ^ r;
                f16x8 bf = *(const f16x8*)(wlds + (ct * 16 + r) * 128 + sc * 8);
                acc0 = __builtin_amdgcn_mfma_f32_16x16x32_f16(aa[kc], bf, acc0, 0, 0, 0);
                acc1 = __builtin_amdgcn_mfma_f32_16x16x32_f16(ab[kc], bf, acc1, 0, 0, 0);
            }
            float m0 = -INFINITY, m1 = -INFINITY;
            #pragma unroll
            for (int i = 0; i < 4; ++i) {         // C row kg*4+i = neighbor k index
                m0 = fmaxf(m0, (acc0[i] + bha[ct]) * wa[i]);
                m1 = fmaxf(m1, (acc1[i] + bhb[ct]) * wb[i]);
            }
            m0 = fmaxf(m0, __shfl_xor(m0, 16, 64));   // reduce across kg groups
            m0 = fmaxf(m0, __shfl_xor(m0, 32, 64));
            m1 = fmaxf(m1, __shfl_xor(m1, 16, 64));
            m1 = fmaxf(m1, __shfl_xor(m1, 32, 64));
            if (kg == 0) {
                out[(size_t)n0 * D + ct * 16 + r] = m0;
                out[(size_t)n1 * D + ct * 16 + r] = m1;
            }
        }
    }
}

extern "C" void kernel_launch(void* const* d_in, const int* in_sizes, int n_in,
                              void* d_out, int out_size, void* d_ws, size_t ws_size,
                              hipStream_t stream) {
    const float* fp  = (const float*)d_in[0];   // (N,128) f32
    const int*   idx = (const int*)d_in[1];     // (N,16) int32
    const float* W   = (const float*)d_in[2];   // (128,256) f32
    const float* b   = (const float*)d_in[3];   // (128,) f32
    float* out = (float*)d_out;                 // (N,128) f32

    char* ws = (char*)d_ws;
    f16* fph   = (f16*)ws;                                   // 12.8 MB
    f16* baseh = fph + (size_t)NROWS * D;                    // 12.8 MB
    float* inv_norm = (float*)(ws + (size_t)2 * NROWS * D * 2);  // 200 KB

    gemm_kernel<<<(NROWS + 127) / 128, 512, 0, stream>>>(fp, W, b, fph, baseh, inv_norm);
    main_kernel<<<1250, 256, 0, stream>>>(W, fph, baseh, idx, inv_norm, out);
}

// Round 7
// 74.972 us; speedup vs baseline: 1.1677x; 1.1677x over previous
//
#include <hip/hip_runtime.h>
#include <hip/hip_fp16.h>
#include <math.h>

#define NROWS 50000
#define D 128
#define KNB 16

typedef _Float16 f16;
typedef _Float16 f16x8 __attribute__((ext_vector_type(8)));
typedef float f32x4 __attribute__((ext_vector_type(4)));

// ---- gemm: stage W2(f16,swizzled,32KB); per wave 16 rows: fph(f16), inv_norm, baseh(f16) ----
__global__ __launch_bounds__(512) void gemm_kernel(const float* __restrict__ fp,
                                                   const float* __restrict__ W,
                                                   const float* __restrict__ b,
                                                   f16* __restrict__ fph,
                                                   f16* __restrict__ baseh,
                                                   float* __restrict__ inv_norm) {
    __shared__ f16 wlds[128 * 128];  // W2[col][k], chunk-swizzled: chunk ^= (col&15)
    int tid = threadIdx.x;
    #pragma unroll
    for (int it = 0; it < 4; ++it) {
        int g = tid + it * 512;
        int i = g * 8;                 // 0..16383
        int c = i >> 7;                // output col 0..127
        int k0 = i & 127;
        int chunk = (k0 >> 3) ^ (c & 15);
        f32x4 v0 = *(const f32x4*)(W + (size_t)c * 256 + 128 + k0);
        f32x4 v1 = *(const f32x4*)(W + (size_t)c * 256 + 128 + k0 + 4);
        f16x8 h;
        #pragma unroll
        for (int e = 0; e < 4; ++e) { h[e] = (f16)v0[e]; h[4 + e] = (f16)v1[e]; }
        *(f16x8*)(wlds + c * 128 + chunk * 8) = h;
    }
    __syncthreads();

    int wid = tid >> 6, lane = tid & 63;
    int row0 = blockIdx.x * 128 + wid * 16;
    if (row0 >= NROWS) return;         // no barriers after this point
    int r = lane & 15, kg = lane >> 4;

    const float* src = fp + (size_t)(row0 + r) * D + kg * 8;
    f32x4 v[8];
    float ssq = 0.f;
    #pragma unroll
    for (int kc = 0; kc < 4; ++kc) {
        v[2 * kc]     = *(const f32x4*)(src + kc * 32);
        v[2 * kc + 1] = *(const f32x4*)(src + kc * 32 + 4);
        #pragma unroll
        for (int e = 0; e < 4; ++e) {
            ssq = fmaf(v[2 * kc][e], v[2 * kc][e], ssq);
            ssq = fmaf(v[2 * kc + 1][e], v[2 * kc + 1][e], ssq);
        }
    }
    ssq += __shfl_xor(ssq, 16, 64);
    ssq += __shfl_xor(ssq, 32, 64);
    if (kg == 0) inv_norm[row0 + r] = rsqrtf(ssq);

    f16x8 a[4];
    #pragma unroll
    for (int kc = 0; kc < 4; ++kc) {
        f16x8 h;
        #pragma unroll
        for (int e = 0; e < 4; ++e) { h[e] = (f16)v[2 * kc][e]; h[4 + e] = (f16)v[2 * kc + 1][e]; }
        a[kc] = h;
        *(f16x8*)(fph + (size_t)(row0 + r) * D + kc * 32 + kg * 8) = h;
    }

    #pragma unroll
    for (int ct = 0; ct < 8; ++ct) {
        int col = ct * 16 + r;
        f32x4 acc = {0.f, 0.f, 0.f, 0.f};
        #pragma unroll
        for (int kc = 0; kc < 4; ++kc) {
            int sc = (kc * 4 + kg) ^ r;  // matches staging XOR
            f16x8 bf = *(const f16x8*)(wlds + col * 128 + sc * 8);
            acc = __builtin_amdgcn_mfma_f32_16x16x32_f16(a[kc], bf, acc, 0, 0, 0);
        }
        float bias = b[col];
        #pragma unroll
        for (int i = 0; i < 4; ++i)
            baseh[(size_t)(row0 + kg * 4 + i) * D + col] = (f16)(acc[i] + bias);
    }
}

// ---- main: ONE pair per wave (grid 6250x256 = 25000 waves); all global loads issued
//      before the barrier so gather latency overlaps W1->LDS staging. ----
__global__ __launch_bounds__(256, 4) void main_kernel(const float* __restrict__ W,
                                                      const f16* __restrict__ fph,
                                                      const f16* __restrict__ baseh,
                                                      const int* __restrict__ idx,
                                                      const float* __restrict__ inv_norm,
                                                      float* __restrict__ out) {
    __shared__ f16 wlds[128 * 128];  // W1[col][k], chunk-swizzled
    int tid = threadIdx.x;
    #pragma unroll
    for (int it = 0; it < 8; ++it) {
        int g = tid + it * 256;
        int i = g * 8;
        int c = i >> 7;
        int k0 = i & 127;
        int chunk = (k0 >> 3) ^ (c & 15);
        f32x4 v0 = *(const f32x4*)(W + (size_t)c * 256 + k0);
        f32x4 v1 = *(const f32x4*)(W + (size_t)c * 256 + k0 + 4);
        f16x8 h;
        #pragma unroll
        for (int e = 0; e < 4; ++e) { h[e] = (f16)v0[e]; h[4 + e] = (f16)v1[e]; }
        *(f16x8*)(wlds + c * 128 + chunk * 8) = h;
    }

    int wid = tid >> 6, lane = tid & 63;
    int r = lane & 15, kg = lane >> 4;
    int pw = blockIdx.x * 4 + wid;       // 0..24999
    int n0 = 2 * pw, n1 = n0 + 1;

    // --- issue every global load before the barrier (overlap with staging) ---
    int ja = idx[(size_t)n0 * KNB + r];
    int jb = idx[(size_t)n1 * KNB + r];
    float rna = inv_norm[n0], rnb = inv_norm[n1];

    f16x8 y0[4], y1[4];                  // B-frags for cosine: broadcast rows n0/n1
    #pragma unroll
    for (int kc = 0; kc < 4; ++kc) {
        y0[kc] = *(const f16x8*)(fph + (size_t)n0 * D + kc * 32 + kg * 8);
        y1[kc] = *(const f16x8*)(fph + (size_t)n1 * D + kc * 32 + kg * 8);
    }
    float bha[8], bhb[8];
    #pragma unroll
    for (int ct = 0; ct < 8; ++ct) {
        bha[ct] = (float)baseh[(size_t)n0 * D + ct * 16 + r];
        bhb[ct] = (float)baseh[(size_t)n1 * D + ct * 16 + r];
    }

    // gathered neighbor rows (A-frags for both cosine and Y-recompute)
    f16x8 aa[4], ab[4];
    #pragma unroll
    for (int kc = 0; kc < 4; ++kc) {
        aa[kc] = *(const f16x8*)(fph + (size_t)ja * D + kc * 32 + kg * 8);
        ab[kc] = *(const f16x8*)(fph + (size_t)jb * D + kc * 32 + kg * 8);
    }
    float rja[4], rjb[4];
    #pragma unroll
    for (int i = 0; i < 4; ++i) {
        rja[i] = inv_norm[__shfl(ja, kg * 4 + i, 64)];
        rjb[i] = inv_norm[__shfl(jb, kg * 4 + i, 64)];
    }

    __syncthreads();                     // wlds ready

    // cosine via MFMA: C[row=k][*] = dot(fp[j_k], fp[n])
    f32x4 ca = {0.f, 0.f, 0.f, 0.f}, cb = {0.f, 0.f, 0.f, 0.f};
    #pragma unroll
    for (int kc = 0; kc < 4; ++kc)
        ca = __builtin_amdgcn_mfma_f32_16x16x32_f16(aa[kc], y0[kc], ca, 0, 0, 0);
    #pragma unroll
    for (int kc = 0; kc < 4; ++kc)
        cb = __builtin_amdgcn_mfma_f32_16x16x32_f16(ab[kc], y1[kc], cb, 0, 0, 0);
    float wa[4], wb[4];
    #pragma unroll
    for (int i = 0; i < 4; ++i) {
        wa[i] = ca[i] * rna * rja[i];
        wb[i] = cb[i] * rnb * rjb[i];
    }

    // Y-recompute + combine; C-in = base (broadcast over the 4 k-rows)
    #pragma unroll
    for (int ct = 0; ct < 8; ++ct) {
        f32x4 acc0 = {bha[ct], bha[ct], bha[ct], bha[ct]};
        f32x4 acc1 = {bhb[ct], bhb[ct], bhb[ct], bhb[ct]};
        #pragma unroll
        for (int kc = 0; kc < 4; ++kc) {
            int sc = (kc * 4 + kg) ^ r;
            f16x8 bf = *(const f16x8*)(wlds + (ct * 16 + r) * 128 + sc * 8);
            acc0 = __builtin_amdgcn_mfma_f32_16x16x32_f16(aa[kc], bf, acc0, 0, 0, 0);
            acc1 = __builtin_amdgcn_mfma_f32_16x16x32_f16(ab[kc], bf, acc1, 0, 0, 0);
        }
        float m0 = -INFINITY, m1 = -INFINITY;
        #pragma unroll
        for (int i = 0; i < 4; ++i) {    // C row kg*4+i = neighbor k index
            m0 = fmaxf(m0, acc0[i] * wa[i]);
            m1 = fmaxf(m1, acc1[i] * wb[i]);
        }
        m0 = fmaxf(m0, __shfl_xor(m0, 16, 64));
        m0 = fmaxf(m0, __shfl_xor(m0, 32, 64));
        m1 = fmaxf(m1, __shfl_xor(m1, 16, 64));
        m1 = fmaxf(m1, __shfl_xor(m1, 32, 64));
        if (kg == 0) {
            out[(size_t)n0 * D + ct * 16 + r] = m0;
            out[(size_t)n1 * D + ct * 16 + r] = m1;
        }
    }
}

extern "C" void kernel_launch(void* const* d_in, const int* in_sizes, int n_in,
                              void* d_out, int out_size, void* d_ws, size_t ws_size,
                              hipStream_t stream) {
    const float* fp  = (const float*)d_in[0];   // (N,128) f32
    const int*   idx = (const int*)d_in[1];     // (N,16) int32
    const float* W   = (const float*)d_in[2];   // (128,256) f32
    const float* b   = (const float*)d_in[3];   // (128,) f32
    float* out = (float*)d_out;                 // (N,128) f32

    char* ws = (char*)d_ws;
    f16* fph   = (f16*)ws;                                   // 12.8 MB
    f16* baseh = fph + (size_t)NROWS * D;                    // 12.8 MB
    float* inv_norm = (float*)(ws + (size_t)2 * NROWS * D * 2);  // 200 KB

    gemm_kernel<<<(NROWS + 127) / 128, 512, 0, stream>>>(fp, W, b, fph, baseh, inv_norm);
    main_kernel<<<6250, 256, 0, stream>>>(W, fph, baseh, idx, inv_norm, out);
}